// Round 2
// baseline (491.572 us; speedup 1.0000x reference)
//
#include <hip/hip_runtime.h>
#include <hip/hip_bf16.h>
#include <math.h>

#define E 4
#define B 8192
#define F 2048
#define L 100
#define NROWS (E * B)          // 32768
#define LAMBDA 1.0f

typedef __attribute__((ext_vector_type(8))) short bf16x8;
typedef __attribute__((ext_vector_type(4))) float f32x4;

static __device__ inline unsigned short f2bf(float x) {
    unsigned u = __float_as_uint(x);
    unsigned r = (u + 0x7FFFu + ((u >> 16) & 1u)) >> 16;   // RNE
    return (unsigned short)r;
}

// ---- sums geometry ----
#define SG 4
#define NSG 25                 // 25 * 4 = 100 labels
#define SBS 8
#define SRW (B / SBS)          // 1024 rows per slice
#define NSUM (E * SBS * NSG)   // 800 blocks

// ---- gemm geometry ----
#define GBM 128                // feats rows per block (8 waves x 16 rows)
#define NGEMM (NROWS / GBM)    // 256 blocks

// --------- K1: W[2048][100] f32 -> Wt[112][2048] bf16 (transposed+pad) ------
// Coalesced LDS-transpose; also folds all zero-init (replaces 2 memsets).
__global__ void __launch_bounds__(256) k_prep(const float* __restrict__ W,
                                              unsigned short* __restrict__ Wt,
                                              float* __restrict__ ce_accum,
                                              int* __restrict__ counts) {
    __shared__ float st[64][101];
    int t = threadIdx.x;
    int b = blockIdx.x;                      // 32 blocks, 64 k-rows each
    if (b == 0) {
        for (int i = t; i < E * L; i += 256) counts[i] = 0;
        if (t == 0) ce_accum[0] = 0.f;
    }
    int k0 = b * 64;
    for (int i = t; i < 64 * 100; i += 256) {
        st[i / 100][i % 100] = W[(size_t)k0 * L + i];
    }
    __syncthreads();
    for (int i = t; i < 112 * 32; i += 256) {
        int n = i >> 5, kp = i & 31;
        unsigned lo = 0, hi = 0;
        if (n < L) {
            lo = f2bf(st[kp * 2][n]);
            hi = f2bf(st[kp * 2 + 1][n]);
        }
        *(unsigned*)&Wt[(size_t)n * F + k0 + kp * 2] = lo | (hi << 16);
    }
}

// round-half-up pack of two f32 -> packed bf16x2 (hi<<16 | lo)
static __device__ inline unsigned pack_bf(float lo, float hi) {
    unsigned ul = __float_as_uint(lo) + 0x8000u;
    unsigned uh = __float_as_uint(hi) + 0x8000u;
    return __builtin_amdgcn_perm(uh, ul, 0x07060302u);
}

// ---- K2: merged main kernel. Blocks [0,256) = barrier-free reg-direct MFMA
// gemm+CE over 128 rows; blocks [256,1056) = tagged-stream label sums.
__global__ void __launch_bounds__(512, 4) k_main(const float* __restrict__ feats,
                                                 const int* __restrict__ y,
                                                 const unsigned short* __restrict__ Wt,
                                                 const float* __restrict__ bias,
                                                 float* __restrict__ partial,
                                                 int* __restrict__ counts,
                                                 float* __restrict__ ce_accum) {
    __shared__ __align__(16) char sm[6208];
    int t = threadIdx.x;

    if (blockIdx.x < NGEMM) {
        // ============ GEMM + CE: no LDS, no barriers in the K-loop ==========
        float* red = (float*)sm;                 // 8 floats
        int wave = t >> 6, lane = t & 63;
        int quad = lane >> 4, l16 = lane & 15;
        int row = blockIdx.x * GBM + wave * 16 + l16;   // this lane's feats row
        const float* ap = feats + (size_t)row * F + quad * 8;
        const unsigned short* wbase = Wt + (size_t)l16 * F + quad * 8;

        f32x4 acc[7];
#pragma unroll
        for (int ct = 0; ct < 7; ++ct) acc[ct] = (f32x4){0.f, 0.f, 0.f, 0.f};

        // 64 K-steps of 32; A fragment = 8 consecutive f32 of own row,
        // W fragment = 8 consecutive bf16 of row ct*16+l16. Same-row lanes
        // (4 quads) cover contiguous 128 B (A) / 64 B (W) segments.
        float4 na0 = ((const float4*)ap)[0];
        float4 na1 = ((const float4*)ap)[1];
#pragma unroll 2
        for (int kk = 0; kk < F / 32; ++kk) {
            float4 a0 = na0, a1 = na1;
            if (kk + 1 < F / 32) {
                const float* apn = ap + (size_t)(kk + 1) * 32;
                na0 = ((const float4*)apn)[0];
                na1 = ((const float4*)apn)[1];
            }
            union { unsigned w[4]; bf16x8 v; } bb;
            bb.w[0] = pack_bf(a0.x, a0.y);
            bb.w[1] = pack_bf(a0.z, a0.w);
            bb.w[2] = pack_bf(a1.x, a1.y);
            bb.w[3] = pack_bf(a1.z, a1.w);
#pragma unroll
            for (int ct = 0; ct < 7; ++ct) {
                bf16x8 af = *(const bf16x8*)(wbase + (size_t)ct * 16 * F + kk * 32);
                acc[ct] = __builtin_amdgcn_mfma_f32_16x16x32_bf16(af, bb.v, acc[ct], 0, 0, 0);
            }
        }

        // fused softmax-CE epilogue (D: lane&15 = feats row, col = 16*ct+quad*4+r)
        int lab = y[row];
        float vv[7][4];
        float vm = -1e30f;
#pragma unroll
        for (int ct = 0; ct < 7; ++ct) {
#pragma unroll
            for (int r = 0; r < 4; ++r) {
                int c = ct * 16 + quad * 4 + r;
                float bb2 = (c < L) ? bias[c] : 0.f;
                float v = acc[ct][r] + bb2;
                vv[ct][r] = v;
                if (c < L) vm = fmaxf(vm, v);
            }
        }
        vm = fmaxf(vm, __shfl_xor(vm, 16));
        vm = fmaxf(vm, __shfl_xor(vm, 32));
        float se = 0.f, tv = 0.f;
#pragma unroll
        for (int ct = 0; ct < 7; ++ct) {
#pragma unroll
            for (int r = 0; r < 4; ++r) {
                int c = ct * 16 + quad * 4 + r;
                if (c < L) se += __expf(vv[ct][r] - vm);
                if (c == lab) tv = vv[ct][r];
            }
        }
        se += __shfl_xor(se, 16);
        se += __shfl_xor(se, 32);
        tv += __shfl_xor(tv, 16);
        tv += __shfl_xor(tv, 32);
        float ce = vm + __logf(se) - tv;
#pragma unroll
        for (int s = 1; s <= 8; s <<= 1) ce += __shfl_xor(ce, s);
        if (lane == 0) red[wave] = ce;
        __syncthreads();
        if (t == 0) {
            float v = 0.f;
#pragma unroll
            for (int w = 0; w < 8; ++w) v += red[w];
            atomicAdd(ce_accum, v);
        }
    } else {
        // ================= tagged-stream label sums =================
        int* ys = (int*)sm;                                   // 4096 B
        unsigned short* list = (unsigned short*)(sm + 4096);  // 2048 B
        int* cnt4 = (int*)(sm + 4096 + 2048);                 // 16 B
        int* ntot = (int*)(sm + 4096 + 2048 + 16);            // 4 B
        int bi = blockIdx.x - NGEMM;
        int lg = bi % NSG;
        int bs = (bi / NSG) % SBS;
        int e  = bi / (NSG * SBS);
        int lab0 = lg * SG;

        if (t < SG) cnt4[t] = 0;
        if (t == 8) ntot[0] = 0;
        const int* yb = y + e * B + bs * SRW;
        ys[t] = yb[t];
        ys[t + 512] = yb[t + 512];
        __syncthreads();

        for (int r = t; r < SRW; r += 512) {
            int lb = ys[r] - lab0;
            if ((unsigned)lb < SG) {
                atomicAdd(&cnt4[lb], 1);
                int p = atomicAdd(ntot, 1);
                list[p] = (unsigned short)(r | (lb << 10));
            }
        }
        __syncthreads();
        int n = ntot[0];
        int npad = (n + 3) & ~3;
        if (t < npad - n) list[n + t] = 0;   // pad rows (guarded out below)
        __syncthreads();

        const float* fb = feats + ((size_t)e * B + (size_t)bs * SRW) * F + t * 4;
        float4 a0 = make_float4(0.f, 0.f, 0.f, 0.f);
        float4 a1 = a0, a2 = a0, a3 = a0;

        float4 x[4];
        int tg[4];
        if (n > 0) {
#pragma unroll
            for (int j = 0; j < 4; ++j) {
                int ev = list[j];
                tg[j] = ev >> 10;
                x[j] = *(const float4*)(fb + (size_t)(ev & 1023) * F);
            }
            for (int i = 0; i < npad; i += 4) {
                float4 nx[4];
                int ntg[4];
                if (i + 4 < npad) {
#pragma unroll
                    for (int j = 0; j < 4; ++j) {
                        int ev = list[i + 4 + j];
                        ntg[j] = ev >> 10;
                        nx[j] = *(const float4*)(fb + (size_t)(ev & 1023) * F);
                    }
                }
#pragma unroll
                for (int j = 0; j < 4; ++j) {
                    if (i + j < n) {   // uniform across block
                        float4 v = x[j];
                        int g = tg[j];  // uniform across block
                        if (g == 0)      { a0.x += v.x; a0.y += v.y; a0.z += v.z; a0.w += v.w; }
                        else if (g == 1) { a1.x += v.x; a1.y += v.y; a1.z += v.z; a1.w += v.w; }
                        else if (g == 2) { a2.x += v.x; a2.y += v.y; a2.z += v.z; a2.w += v.w; }
                        else             { a3.x += v.x; a3.y += v.y; a3.z += v.z; a3.w += v.w; }
                    }
                }
#pragma unroll
                for (int j = 0; j < 4; ++j) { x[j] = nx[j]; tg[j] = ntg[j]; }
            }
        }

        float* pb = partial + (((size_t)e * SBS + bs) * L + lab0) * F + t * 4;
        *(float4*)(pb + 0 * F) = a0;   // unconditional: partial is poisoned
        *(float4*)(pb + 1 * F) = a1;
        *(float4*)(pb + 2 * F) = a2;
        *(float4*)(pb + 3 * F) = a3;
        if (t < SG) atomicAdd(&counts[e * L + lab0 + t], cnt4[t]);
    }
}

// -------- K3: partial[e][bs][l][f] -> per-(e,l) variance over feature dim ---
__global__ void __launch_bounds__(512) k_var(const float* __restrict__ partial,
                                             const int* __restrict__ counts,
                                             float* __restrict__ var_out) {
    int el = blockIdx.x;  // e*L + l
    int e = el / L, l = el % L;
    int t = threadIdx.x;
    float inv = 1.f / fmaxf((float)counts[el], 1.f);
    float4 s = make_float4(0.f, 0.f, 0.f, 0.f);
#pragma unroll
    for (int bs = 0; bs < SBS; ++bs) {
        float4 v = *(const float4*)&partial[(((size_t)e * SBS + bs) * L + l) * F + t * 4];
        s.x += v.x; s.y += v.y; s.z += v.z; s.w += v.w;
    }
    float mx = s.x * inv, my = s.y * inv, mz = s.z * inv, mw = s.w * inv;
    float sm = mx + my + mz + mw;
    float sm2 = mx * mx + my * my + mz * mz + mw * mw;
#pragma unroll
    for (int sft = 1; sft <= 32; sft <<= 1) {
        sm += __shfl_xor(sm, sft);
        sm2 += __shfl_xor(sm2, sft);
    }
    __shared__ float r1[8], r2[8];
    int wv = t >> 6, ln = t & 63;
    if (ln == 0) { r1[wv] = sm; r2[wv] = sm2; }
    __syncthreads();
    if (t == 0) {
        float S = 0.f, S2 = 0.f;
#pragma unroll
        for (int w = 0; w < 8; ++w) { S += r1[w]; S2 += r2[w]; }
        var_out[el] = (S2 - S * S / (float)F) / (float)(F - 1);
    }
}

// ------------------------- K4: final scalar combine -------------------------
__global__ void k_final(const int* __restrict__ counts,
                        const float* __restrict__ var_in,
                        const float* __restrict__ ce_accum,
                        float* __restrict__ out) {
    __shared__ float s_sum[128], s_cnt[128];
    int t = threadIdx.x;
    float selsum = 0.f, selcnt = 0.f;
    for (int l = t; l < L; l += 128) {
        float nvis = 0.f, vsum = 0.f;
        for (int e = 0; e < E; ++e) {
            if (counts[e * L + l] > 0) { nvis += 1.f; vsum += var_in[e * L + l]; }
        }
        float per_label = vsum / fmaxf(nvis, 1.f);
        if (nvis > 1.5f) { selsum += per_label; selcnt += 1.f; }
    }
    s_sum[t] = selsum; s_cnt[t] = selcnt;
    __syncthreads();
    for (int s = 64; s > 0; s >>= 1) {
        if (t < s) { s_sum[t] += s_sum[t + s]; s_cnt[t] += s_cnt[t + s]; }
        __syncthreads();
    }
    if (t == 0) {
        float mean_loss = LAMBDA * s_sum[0] / fmaxf(s_cnt[0], 1.f);
        float ce = ce_accum[0] / (float)NROWS;
        out[0] = mean_loss + ce;
    }
}

extern "C" void kernel_launch(void* const* d_in, const int* in_sizes, int n_in,
                              void* d_out, int out_size, void* d_ws, size_t ws_size,
                              hipStream_t stream) {
    const float* feats = (const float*)d_in[0];
    const int*   y     = (const int*)d_in[1];
    const float* Wm    = (const float*)d_in[2];
    const float* bias  = (const float*)d_in[3];
    float* out = (float*)d_out;

    char* ws = (char*)d_ws;
    float*          ce_accum = (float*)ws;                  // 4 B
    int*            counts   = (int*)(ws + 256);            // 1600 B
    float*          var_buf  = (float*)(ws + 2048);         // 1600 B
    float*          partial  = (float*)(ws + 4096);         // E*SBS*L*F*4 = 26.2 MB
    unsigned short* Wt       = (unsigned short*)(ws + 4096 + (size_t)E * SBS * L * F * 4); // 458 KB

    k_prep<<<F / 64, 256, 0, stream>>>(Wm, Wt, ce_accum, counts);
    k_main<<<NGEMM + NSUM, 512, 0, stream>>>(feats, y, Wt, bias, partial, counts, ce_accum);
    k_var<<<E * L, 512, 0, stream>>>(partial, counts, var_buf);
    k_final<<<1, 128, 0, stream>>>(counts, var_buf, ce_accum, out);
}